// Round 8
// baseline (298.532 us; speedup 1.0000x reference)
//
#include <hip/hip_runtime.h>
#include <hip/hip_bf16.h>

#define NROW_F 8192
#define NROW_B 65536
#define KDIM   384
#define BM 256
#define BN 256
#define NSUB 8
#define NGRP (NROW_B / (BN * NSUB))      // 32
#define NBM  (NROW_F / BM)               // 32
#define NWG  (NBM * NGRP)                // 1024

// LDS map (bytes): A 6 K-tiles resident, B triple-buffered, sB slice, red aliases B
#define LDSA 0                 // 6 * 16384 = 98304
#define LDSB 98304             // 3 * 16384 = 49152
#define LDSS 147456            // 8192 (2048 f32 sB slice)
#define LDSR 98304             // epilogue red[4][256] aliases B bufs
#define LDS_TOT 155648

typedef int   i32x4 __attribute__((ext_vector_type(4)));
typedef float f32x4 __attribute__((ext_vector_type(4)));

static __device__ __forceinline__ void stage16(const void* g, void* l) {
  __builtin_amdgcn_global_load_lds(
      (const __attribute__((address_space(1))) unsigned int*)g,
      (__attribute__((address_space(3))) unsigned int*)l, 16, 0, 0);
}

// ---------------------------------------------------------------------------
// 1) L2-normalize rows + symmetric i8 quantization with per-row scale.
// ---------------------------------------------------------------------------
__global__ __launch_bounds__(256) void quantize_rows_kernel(
    const float* __restrict__ in, char* __restrict__ out8,
    float* __restrict__ scales, int nrows) {
  int row  = blockIdx.x * 4 + (threadIdx.x >> 6);
  int lane = threadIdx.x & 63;
  if (row >= nrows) return;
  const float* r = in + (size_t)row * KDIM;
  float v[6];
  float ss = 0.f, mx = 0.f;
#pragma unroll
  for (int i = 0; i < 6; ++i) {
    v[i] = r[lane + i * 64];
    ss += v[i] * v[i];
    mx = fmaxf(mx, fabsf(v[i]));
  }
#pragma unroll
  for (int d = 1; d < 64; d <<= 1) {
    ss += __shfl_xor(ss, d, 64);
    mx = fmaxf(mx, __shfl_xor(mx, d, 64));
  }
  mx = fmaxf(mx, 1e-30f);
  float inv = rsqrtf(fmaxf(ss, 1e-24f));
  float scl = 127.0f / mx;
  if (lane == 0) scales[row] = mx * inv * (1.0f / 127.0f);
  char* o = out8 + (size_t)row * KDIM;
#pragma unroll
  for (int i = 0; i < 6; ++i)
    o[lane + i * 64] = (char)__float2int_rn(v[i] * scl);
}

// ---------------------------------------------------------------------------
// 2) maxsim: i8 MFMA 16x16x64, A LDS-resident, B tri-buffered vmcnt(4).
//    Software-pipelined: A-frags for k6+1 prefetched into registers during
//    k6's MFMA cluster, so the pre-MFMA lgkmcnt(0) covers only 4 B-reads.
// ---------------------------------------------------------------------------
__global__ __launch_bounds__(512) void maxsim_kernel(
    const char* __restrict__ F8,    // 8192 x 384 i8
    const char* __restrict__ B8,    // 65536 x 384 i8
    const float* __restrict__ sA,   // 8192
    const float* __restrict__ sB,   // 65536
    float* __restrict__ partial) {  // NGRP x 8192 (max sim)
  __shared__ __align__(16) char smem[LDS_TOT];

  const int tid  = threadIdx.x;
  const int wv   = tid >> 6;
  const int lane = tid & 63;
  const int l15  = lane & 15;
  const int lhi  = lane >> 4;
  const int wr   = wv >> 2;          // 0..1
  const int wc   = wv & 3;           // 0..3

  // XCD-bijective swizzle (NWG % 8 == 0); co-resident blocks share grp.
  const int wg  = (blockIdx.x & 7) * (NWG / 8) + (blockIdx.x >> 3);
  const int bm  = wg & (NBM - 1);
  const int grp = wg >> 5;
  const size_t brow = (size_t)bm * BM;

  // ---- staging geometry: 16KB tile = 256 rows x 64B; wave = 32 rows ----
  const int srow16 = lane >> 2;                        // row within 16-row grp
  const int gsw    = (lane & 3) ^ ((lane >> 3) & 3);   // inverse write swizzle

  // A prologue: 6 K-tiles staged once (12 issues/thread)
  {
    const char* gA = F8 + ((size_t)(brow + wv * 32 + srow16)) * KDIM + gsw * 16;
    char* lA = smem + LDSA + wv * 2048;
#pragma unroll
    for (int kt = 0; kt < 6; ++kt) {
      stage16(gA + kt * 64,              lA + kt * 16384);
      stage16(gA + kt * 64 + 16 * KDIM,  lA + kt * 16384 + 1024);
    }
  }
  // sB slice (2048 floats = 8KB): PER-LANE source (+ lane*16), uniform dest.
  stage16((const char*)(sB + (size_t)grp * 2048) + wv * 1024 + lane * 16,
          smem + LDSS + wv * 1024);

  auto stageB = [&](int kt, int buf) {
    const char* g = B8 + ((size_t)grp * 2048 + (kt / 6) * 256 + wv * 32 + srow16) * KDIM
                    + (kt % 6) * 64 + gsw * 16;
    char* l = smem + LDSB + buf * 16384 + wv * 2048;
    stage16(g, l);
    stage16(g + 16 * KDIM, l + 1024);
  };
  stageB(0, 0);
  stageB(1, 1);

  // read-side swizzle: chunk(lhi) ^= (row>>1)&3, row ≡ l15 (bases mult of 16)
  const int cof = ((l15 >> 1) & 3) << 4;

  auto ldA8 = [&](int k6, int m) -> i32x4 {
    int byte = k6 * 16384 + (wr * 128 + m * 16 + l15) * 64 + ((lhi << 4) ^ cof);
    return *reinterpret_cast<const i32x4*>(smem + LDSA + byte);
  };
  auto ldB8 = [&](int buf, int n) -> i32x4 {
    int byte = buf * 16384 + (wc * 64 + n * 16 + l15) * 64 + ((lhi << 4) ^ cof);
    return *reinterpret_cast<const i32x4*>(smem + LDSB + byte);
  };

  i32x4 acc[8][4];
  f32x4 vm[8];
#pragma unroll
  for (int m = 0; m < 8; ++m) {
    vm[m] = f32x4{-1e30f, -1e30f, -1e30f, -1e30f};
#pragma unroll
    for (int n = 0; n < 4; ++n) acc[m][n] = i32x4{0, 0, 0, 0};
  }

  // Drain everything except B1 (2 newest) so reads of A / buf0 are safe.
  asm volatile("s_waitcnt vmcnt(2)" ::: "memory");
  __builtin_amdgcn_s_barrier();

  // A-frag register pipeline: areg[parity][m]; k6 unrolled -> static indices.
  i32x4 areg[2][8];
#pragma unroll
  for (int m = 0; m < 8; ++m) areg[0][m] = ldA8(0, m);

  for (int sub = 0; sub < NSUB; ++sub) {
#pragma unroll
    for (int k6 = 0; k6 < 6; ++k6) {
      const int kt = sub * 6 + k6;
      // ALWAYS stage (wrap at tail) so the vmcnt(4) ledger stays exact.
      stageB((kt + 2) % (NSUB * 6), (k6 + 2) % 3);
      asm volatile("s_waitcnt vmcnt(4)" ::: "memory");
      __builtin_amdgcn_s_barrier();

      i32x4 b[4];
#pragma unroll
      for (int n = 0; n < 4; ++n) b[n] = ldB8(k6 % 3, n);
      // waits 4 B-reads + any A-prefetch from previous phase
      asm volatile("s_waitcnt lgkmcnt(0)" ::: "memory");
      __builtin_amdgcn_sched_barrier(0);
      __builtin_amdgcn_s_setprio(1);
#pragma unroll
      for (int n = 0; n < 4; ++n)
#pragma unroll
        for (int m = 0; m < 4; ++m)
          acc[m][n] = __builtin_amdgcn_mfma_i32_16x16x64_i8(
              areg[k6 & 1][m], b[n], acc[m][n], 0, 0, 0);
      // prefetch next k6's A-frags (A is resident & read-only: no hazard)
#pragma unroll
      for (int m = 0; m < 8; ++m)
        areg[(k6 + 1) & 1][m] = ldA8((k6 + 1) % 6, m);
#pragma unroll
      for (int n = 0; n < 4; ++n)
#pragma unroll
        for (int m = 4; m < 8; ++m)
          acc[m][n] = __builtin_amdgcn_mfma_i32_16x16x64_i8(
              areg[k6 & 1][m], b[n], acc[m][n], 0, 0, 0);
      __builtin_amdgcn_s_setprio(0);
      asm volatile("" ::: "memory");   // keep this phase's LDS reads above
      __builtin_amdgcn_s_barrier();
    }
    // fold subtile: vm = max(vm, acc * sB[col]); reset acc
    float sb[4];
#pragma unroll
    for (int n = 0; n < 4; ++n)
      sb[n] = *reinterpret_cast<const float*>(
          smem + LDSS + (sub * 256 + wc * 64 + n * 16 + l15) * 4);
#pragma unroll
    for (int m = 0; m < 8; ++m) {
#pragma unroll
      for (int n = 0; n < 4; ++n)
#pragma unroll
        for (int j = 0; j < 4; ++j)
          vm[m][j] = fmaxf(vm[m][j], (float)acc[m][n][j] * sb[n]);
#pragma unroll
      for (int n = 0; n < 4; ++n) acc[m][n] = i32x4{0, 0, 0, 0};
    }
  }

  // ---- epilogue ----
  asm volatile("s_waitcnt vmcnt(0)" ::: "memory");
#pragma unroll
  for (int d = 1; d < 16; d <<= 1)
#pragma unroll
    for (int m = 0; m < 8; ++m)
#pragma unroll
      for (int j = 0; j < 4; ++j)
        vm[m][j] = fmaxf(vm[m][j], __shfl_xor(vm[m][j], d, 64));

  float* red = (float*)(smem + LDSR);
  __syncthreads();
  if (l15 == 0) {
#pragma unroll
    for (int m = 0; m < 8; ++m)
#pragma unroll
      for (int j = 0; j < 4; ++j)
        red[wc * 256 + wr * 128 + m * 16 + lhi * 4 + j] = vm[m][j];
  }
  __syncthreads();
  if (tid < 256) {
    float x = fmaxf(fmaxf(red[tid], red[256 + tid]),
                    fmaxf(red[512 + tid], red[768 + tid]));
    partial[(size_t)grp * NROW_F + brow + tid] = x * sA[brow + tid];
  }
}

// ---------------------------------------------------------------------------
// 3) combine partial maxes -> min_dists = clip(1 - max, 0, 2)
// ---------------------------------------------------------------------------
__global__ __launch_bounds__(256) void combine_kernel(
    const float* __restrict__ partial, float* __restrict__ md) {
  int r = blockIdx.x * 256 + threadIdx.x;
  if (r >= NROW_F) return;
  float m = -1e30f;
#pragma unroll
  for (int c = 0; c < NGRP; ++c) m = fmaxf(m, partial[(size_t)c * NROW_F + r]);
  float d = 1.0f - m;
  d = fminf(fmaxf(d, 0.0f), 2.0f);
  md[r] = d;
}

// ---------------------------------------------------------------------------
// 4) per-batch top-10 mean -> pred_score
// ---------------------------------------------------------------------------
__global__ __launch_bounds__(256) void topk_kernel(
    const float* __restrict__ md, float* __restrict__ out) {
  __shared__ float buf[1024];
  __shared__ float svals[256];
  __shared__ int   sidx[256];
  int b = blockIdx.x, tid = threadIdx.x;
  for (int i = tid; i < 1024; i += 256) buf[i] = md[b * 1024 + i];
  __syncthreads();
  float total = 0.f;
  for (int it = 0; it < 10; ++it) {
    float best = -1e30f; int bi = 0;
    for (int i = tid; i < 1024; i += 256)
      if (buf[i] > best) { best = buf[i]; bi = i; }
    svals[tid] = best; sidx[tid] = bi;
    __syncthreads();
    for (int s = 128; s > 0; s >>= 1) {
      if (tid < s && svals[tid + s] > svals[tid]) {
        svals[tid] = svals[tid + s]; sidx[tid] = sidx[tid + s];
      }
      __syncthreads();
    }
    if (tid == 0) { total += svals[0]; buf[sidx[0]] = -1e30f; }
    __syncthreads();
  }
  if (tid == 0) out[b] = total * 0.1f;
}

// ---------------------------------------------------------------------------
// 5) W = blur_1d ∘ bilinear_resize_1d : 448 x 32 operator.
// ---------------------------------------------------------------------------
__global__ __launch_bounds__(256) void build_w_kernel(float* __restrict__ W) {
  int idx = blockIdx.x * 256 + threadIdx.x;
  if (idx >= 448 * 32) return;
  int y = idx >> 5, g = idx & 31;
  float ksum = 0.f, acc = 0.f;
#pragma unroll
  for (int t = -16; t <= 16; ++t) {
    float ft = (float)t * 0.25f;
    float kv = expf(-0.5f * ft * ft);
    ksum += kv;
    int p = y + t;
    p = (p < 0) ? -p : ((p > 447) ? 894 - p : p);
    float src = ((float)p + 0.5f) * (1.0f / 14.0f) - 0.5f;
    float fl = floorf(src);
    int i0 = (int)fl;
    float fr = src - fl;
    int c0 = i0 < 0 ? 0 : (i0 > 31 ? 31 : i0);
    int i1 = i0 + 1;
    int c1 = i1 < 0 ? 0 : (i1 > 31 ? 31 : i1);
    float w = 0.f;
    if (c0 == g) w += 1.0f - fr;
    if (c1 == g) w += fr;
    acc += kv * w;
  }
  W[idx] = acc / ksum;
}

// ---------------------------------------------------------------------------
// 6) anomaly_map = W · md_grid · W^T
// ---------------------------------------------------------------------------
__global__ __launch_bounds__(256) void map_stage1_kernel(
    const float* __restrict__ md, const float* __restrict__ W,
    float* __restrict__ tmp) {  // 8 x 448 x 32
  int idx = blockIdx.x * 256 + threadIdx.x;
  if (idx >= 8 * 448 * 32) return;
  int gx = idx & 31;
  int y  = (idx >> 5) % 448;
  int b  = idx / (448 * 32);
  const float* w = W + y * 32;
  const float* m = md + b * 1024 + gx;
  float s = 0.f;
#pragma unroll
  for (int gy = 0; gy < 32; ++gy) s += w[gy] * m[gy * 32];
  tmp[idx] = s;
}

__global__ __launch_bounds__(256) void map_stage2_kernel(
    const float* __restrict__ tmp, const float* __restrict__ W,
    float* __restrict__ out) {  // 8 x 448 x 448
  int idx = blockIdx.x * 256 + threadIdx.x;
  if (idx >= 8 * 448 * 448) return;
  int x    = idx % 448;
  int ypos = idx / 448;  // b*448 + y
  const float* w = W + x * 32;
  const float* t = tmp + ypos * 32;
  float s = 0.f;
#pragma unroll
  for (int gx = 0; gx < 32; ++gx) s += w[gx] * t[gx];
  out[idx] = s;
}

// ---------------------------------------------------------------------------
extern "C" void kernel_launch(void* const* d_in, const int* in_sizes, int n_in,
                              void* d_out, int out_size, void* d_ws, size_t ws_size,
                              hipStream_t stream) {
  const float* features = (const float*)d_in[0];   // 8*1024*384
  const float* bank     = (const float*)d_in[1];   // 65536*384
  float* out = (float*)d_out;                      // [8 scores][8*448*448 map]

  char* ws = (char*)d_ws;
  char*  mb8     = ws;                              // 25,165,824 B
  char*  f8      = ws + 25165824;                   //  3,145,728 B
  float* sB      = (float*)(ws + 28311552);         //    262,144 B
  float* sA      = (float*)(ws + 28573696);         //     32,768 B
  float* partial = (float*)(ws + 28606464);         //  1,048,576 B
  float* md      = (float*)(ws + 29655040);         //     32,768 B
  float* W       = (float*)(ws + 29687808);         //     57,344 B
  float* tmp     = (float*)(ws + 29745152);         //    458,752 B

  quantize_rows_kernel<<<NROW_B / 4, 256, 0, stream>>>(bank, mb8, sB, NROW_B);
  quantize_rows_kernel<<<NROW_F / 4, 256, 0, stream>>>(features, f8, sA, NROW_F);
  maxsim_kernel<<<NWG, 512, 0, stream>>>(f8, mb8, sA, sB, partial);
  combine_kernel<<<NROW_F / 256, 256, 0, stream>>>(partial, md);
  topk_kernel<<<8, 256, 0, stream>>>(md, out);
  build_w_kernel<<<(448 * 32 + 255) / 256, 256, 0, stream>>>(W);
  map_stage1_kernel<<<(8 * 448 * 32 + 255) / 256, 256, 0, stream>>>(md, W, tmp);
  map_stage2_kernel<<<(8 * 448 * 448 + 255) / 256, 256, 0, stream>>>(tmp, W, out + 8);
}

// Round 9
// 253.452 us; speedup vs baseline: 1.1779x; 1.1779x over previous
//
#include <hip/hip_runtime.h>
#include <hip/hip_bf16.h>

#define NROW_F 8192
#define NROW_B 65536
#define KDIM   384
#define BM 256
#define BN 256
#define NSUB 8
#define NGRP (NROW_B / (BN * NSUB))      // 32
#define NBM  (NROW_F / BM)               // 32
#define NWG  (NBM * NGRP)                // 1024

// LDS map (bytes): A 6 K-tiles resident, B triple-buffered, sB slice, red aliases B
#define LDSA 0                 // 6 * 16384 = 98304
#define LDSB 98304             // 3 * 16384 = 49152
#define LDSS 147456            // 8192 (2048 f32 sB slice)
#define LDSR 98304             // epilogue red[4][256] aliases B bufs
#define LDS_TOT 155648

typedef int   i32x4 __attribute__((ext_vector_type(4)));
typedef float f32x4 __attribute__((ext_vector_type(4)));

static __device__ __forceinline__ void stage16(const void* g, void* l) {
  __builtin_amdgcn_global_load_lds(
      (const __attribute__((address_space(1))) unsigned int*)g,
      (__attribute__((address_space(3))) unsigned int*)l, 16, 0, 0);
}

// ---------------------------------------------------------------------------
// 1) L2-normalize rows + symmetric i8 quantization with per-row scale.
// ---------------------------------------------------------------------------
__global__ __launch_bounds__(256) void quantize_rows_kernel(
    const float* __restrict__ in, char* __restrict__ out8,
    float* __restrict__ scales, int nrows) {
  int row  = blockIdx.x * 4 + (threadIdx.x >> 6);
  int lane = threadIdx.x & 63;
  if (row >= nrows) return;
  const float* r = in + (size_t)row * KDIM;
  float v[6];
  float ss = 0.f, mx = 0.f;
#pragma unroll
  for (int i = 0; i < 6; ++i) {
    v[i] = r[lane + i * 64];
    ss += v[i] * v[i];
    mx = fmaxf(mx, fabsf(v[i]));
  }
#pragma unroll
  for (int d = 1; d < 64; d <<= 1) {
    ss += __shfl_xor(ss, d, 64);
    mx = fmaxf(mx, __shfl_xor(mx, d, 64));
  }
  mx = fmaxf(mx, 1e-30f);
  float inv = rsqrtf(fmaxf(ss, 1e-24f));
  float scl = 127.0f / mx;
  if (lane == 0) scales[row] = mx * inv * (1.0f / 127.0f);
  char* o = out8 + (size_t)row * KDIM;
#pragma unroll
  for (int i = 0; i < 6; ++i)
    o[lane + i * 64] = (char)__float2int_rn(v[i] * scl);
}

// ---------------------------------------------------------------------------
// 2) maxsim: i8 MFMA 16x16x64, A LDS-resident, B tri-buffered vmcnt(4).
//    Counted-lgkm split: issue a0-3,b0-3,a4-7; lgkmcnt(4) covers first 8
//    (in-order DS completion) -> MFMA half m=0..3 runs while a4-7 land;
//    mid-cluster barrier (all reads done -> next stage safe) -> half m=4..7
//    overlaps other waves' stage+vmcnt. No extra registers (r8 spilled).
// ---------------------------------------------------------------------------
__global__ __launch_bounds__(512) void maxsim_kernel(
    const char* __restrict__ F8,    // 8192 x 384 i8
    const char* __restrict__ B8,    // 65536 x 384 i8
    const float* __restrict__ sA,   // 8192
    const float* __restrict__ sB,   // 65536
    float* __restrict__ partial) {  // NGRP x 8192 (max sim)
  __shared__ __align__(16) char smem[LDS_TOT];

  const int tid  = threadIdx.x;
  const int wv   = tid >> 6;
  const int lane = tid & 63;
  const int l15  = lane & 15;
  const int lhi  = lane >> 4;
  const int wr   = wv >> 2;          // 0..1
  const int wc   = wv & 3;           // 0..3

  // XCD-bijective swizzle (NWG % 8 == 0); co-resident blocks share grp.
  const int wg  = (blockIdx.x & 7) * (NWG / 8) + (blockIdx.x >> 3);
  const int bm  = wg & (NBM - 1);
  const int grp = wg >> 5;
  const size_t brow = (size_t)bm * BM;

  // ---- staging geometry: 16KB tile = 256 rows x 64B; wave = 32 rows ----
  const int srow16 = lane >> 2;                        // row within 16-row grp
  const int gsw    = (lane & 3) ^ ((lane >> 3) & 3);   // inverse write swizzle

  // A prologue: 6 K-tiles staged once (12 issues/thread)
  {
    const char* gA = F8 + ((size_t)(brow + wv * 32 + srow16)) * KDIM + gsw * 16;
    char* lA = smem + LDSA + wv * 2048;
#pragma unroll
    for (int kt = 0; kt < 6; ++kt) {
      stage16(gA + kt * 64,              lA + kt * 16384);
      stage16(gA + kt * 64 + 16 * KDIM,  lA + kt * 16384 + 1024);
    }
  }
  // sB slice (2048 floats = 8KB): PER-LANE source (+ lane*16), uniform dest.
  stage16((const char*)(sB + (size_t)grp * 2048) + wv * 1024 + lane * 16,
          smem + LDSS + wv * 1024);

  auto stageB = [&](int kt, int buf) {
    const char* g = B8 + ((size_t)grp * 2048 + (kt / 6) * 256 + wv * 32 + srow16) * KDIM
                    + (kt % 6) * 64 + gsw * 16;
    char* l = smem + LDSB + buf * 16384 + wv * 2048;
    stage16(g, l);
    stage16(g + 16 * KDIM, l + 1024);
  };
  stageB(0, 0);
  stageB(1, 1);

  // read-side swizzle: chunk(lhi) ^= (row>>1)&3, row ≡ l15 (bases mult of 16)
  const int cof = ((l15 >> 1) & 3) << 4;

  auto ldA8 = [&](int k6, int m) -> i32x4 {
    int byte = k6 * 16384 + (wr * 128 + m * 16 + l15) * 64 + ((lhi << 4) ^ cof);
    return *reinterpret_cast<const i32x4*>(smem + LDSA + byte);
  };
  auto ldB8 = [&](int buf, int n) -> i32x4 {
    int byte = buf * 16384 + (wc * 64 + n * 16 + l15) * 64 + ((lhi << 4) ^ cof);
    return *reinterpret_cast<const i32x4*>(smem + LDSB + byte);
  };

  i32x4 acc[8][4];
  f32x4 vm[8];
#pragma unroll
  for (int m = 0; m < 8; ++m) {
    vm[m] = f32x4{-1e30f, -1e30f, -1e30f, -1e30f};
#pragma unroll
    for (int n = 0; n < 4; ++n) acc[m][n] = i32x4{0, 0, 0, 0};
  }

  for (int sub = 0; sub < NSUB; ++sub) {
#pragma unroll
    for (int k6 = 0; k6 < 6; ++k6) {
      const int kt = sub * 6 + k6;
      // ALWAYS stage (wrap at tail) so the vmcnt(4) ledger stays exact.
      stageB((kt + 2) % (NSUB * 6), (k6 + 2) % 3);
      asm volatile("s_waitcnt vmcnt(4)" ::: "memory");
      __builtin_amdgcn_s_barrier();

      i32x4 a[8], b[4];
#pragma unroll
      for (int m = 0; m < 4; ++m) a[m] = ldA8(k6, m);
#pragma unroll
      for (int n = 0; n < 4; ++n) b[n] = ldB8(k6 % 3, n);
#pragma unroll
      for (int m = 4; m < 8; ++m) a[m] = ldA8(k6, m);

      // first 8 reads (a0-3, b0-3) landed; a4-7 still in flight
      asm volatile("s_waitcnt lgkmcnt(4)" ::: "memory");
      __builtin_amdgcn_sched_barrier(0);
      __builtin_amdgcn_s_setprio(1);
#pragma unroll
      for (int n = 0; n < 4; ++n)
#pragma unroll
        for (int m = 0; m < 4; ++m)
          acc[m][n] = __builtin_amdgcn_mfma_i32_16x16x64_i8(
              a[m], b[n], acc[m][n], 0, 0, 0);
      // a4-7 completed under the MFMA half; all reads done -> stage safe
      asm volatile("s_waitcnt lgkmcnt(0)" ::: "memory");
      __builtin_amdgcn_sched_barrier(0);
      __builtin_amdgcn_s_barrier();
#pragma unroll
      for (int n = 0; n < 4; ++n)
#pragma unroll
        for (int m = 4; m < 8; ++m)
          acc[m][n] = __builtin_amdgcn_mfma_i32_16x16x64_i8(
              a[m], b[n], acc[m][n], 0, 0, 0);
      __builtin_amdgcn_s_setprio(0);
    }
    // fold subtile: vm = max(vm, acc * sB[col]); reset acc
    float sb[4];
#pragma unroll
    for (int n = 0; n < 4; ++n)
      sb[n] = *reinterpret_cast<const float*>(
          smem + LDSS + (sub * 256 + wc * 64 + n * 16 + l15) * 4);
#pragma unroll
    for (int m = 0; m < 8; ++m) {
#pragma unroll
      for (int n = 0; n < 4; ++n)
#pragma unroll
        for (int j = 0; j < 4; ++j)
          vm[m][j] = fmaxf(vm[m][j], (float)acc[m][n][j] * sb[n]);
#pragma unroll
      for (int n = 0; n < 4; ++n) acc[m][n] = i32x4{0, 0, 0, 0};
    }
  }

  // ---- epilogue ----
  asm volatile("s_waitcnt vmcnt(0)" ::: "memory");
#pragma unroll
  for (int d = 1; d < 16; d <<= 1)
#pragma unroll
    for (int m = 0; m < 8; ++m)
#pragma unroll
      for (int j = 0; j < 4; ++j)
        vm[m][j] = fmaxf(vm[m][j], __shfl_xor(vm[m][j], d, 64));

  float* red = (float*)(smem + LDSR);
  __syncthreads();
  if (l15 == 0) {
#pragma unroll
    for (int m = 0; m < 8; ++m)
#pragma unroll
      for (int j = 0; j < 4; ++j)
        red[wc * 256 + wr * 128 + m * 16 + lhi * 4 + j] = vm[m][j];
  }
  __syncthreads();
  if (tid < 256) {
    float x = fmaxf(fmaxf(red[tid], red[256 + tid]),
                    fmaxf(red[512 + tid], red[768 + tid]));
    partial[(size_t)grp * NROW_F + brow + tid] = x * sA[brow + tid];
  }
}

// ---------------------------------------------------------------------------
// 3) combine partial maxes -> min_dists = clip(1 - max, 0, 2)
// ---------------------------------------------------------------------------
__global__ __launch_bounds__(256) void combine_kernel(
    const float* __restrict__ partial, float* __restrict__ md) {
  int r = blockIdx.x * 256 + threadIdx.x;
  if (r >= NROW_F) return;
  float m = -1e30f;
#pragma unroll
  for (int c = 0; c < NGRP; ++c) m = fmaxf(m, partial[(size_t)c * NROW_F + r]);
  float d = 1.0f - m;
  d = fminf(fmaxf(d, 0.0f), 2.0f);
  md[r] = d;
}

// ---------------------------------------------------------------------------
// 4) per-batch top-10 mean -> pred_score
// ---------------------------------------------------------------------------
__global__ __launch_bounds__(256) void topk_kernel(
    const float* __restrict__ md, float* __restrict__ out) {
  __shared__ float buf[1024];
  __shared__ float svals[256];
  __shared__ int   sidx[256];
  int b = blockIdx.x, tid = threadIdx.x;
  for (int i = tid; i < 1024; i += 256) buf[i] = md[b * 1024 + i];
  __syncthreads();
  float total = 0.f;
  for (int it = 0; it < 10; ++it) {
    float best = -1e30f; int bi = 0;
    for (int i = tid; i < 1024; i += 256)
      if (buf[i] > best) { best = buf[i]; bi = i; }
    svals[tid] = best; sidx[tid] = bi;
    __syncthreads();
    for (int s = 128; s > 0; s >>= 1) {
      if (tid < s && svals[tid + s] > svals[tid]) {
        svals[tid] = svals[tid + s]; sidx[tid] = sidx[tid + s];
      }
      __syncthreads();
    }
    if (tid == 0) { total += svals[0]; buf[sidx[0]] = -1e30f; }
    __syncthreads();
  }
  if (tid == 0) out[b] = total * 0.1f;
}

// ---------------------------------------------------------------------------
// 5) W = blur_1d ∘ bilinear_resize_1d : 448 x 32 operator.
// ---------------------------------------------------------------------------
__global__ __launch_bounds__(256) void build_w_kernel(float* __restrict__ W) {
  int idx = blockIdx.x * 256 + threadIdx.x;
  if (idx >= 448 * 32) return;
  int y = idx >> 5, g = idx & 31;
  float ksum = 0.f, acc = 0.f;
#pragma unroll
  for (int t = -16; t <= 16; ++t) {
    float ft = (float)t * 0.25f;
    float kv = expf(-0.5f * ft * ft);
    ksum += kv;
    int p = y + t;
    p = (p < 0) ? -p : ((p > 447) ? 894 - p : p);
    float src = ((float)p + 0.5f) * (1.0f / 14.0f) - 0.5f;
    float fl = floorf(src);
    int i0 = (int)fl;
    float fr = src - fl;
    int c0 = i0 < 0 ? 0 : (i0 > 31 ? 31 : i0);
    int i1 = i0 + 1;
    int c1 = i1 < 0 ? 0 : (i1 > 31 ? 31 : i1);
    float w = 0.f;
    if (c0 == g) w += 1.0f - fr;
    if (c1 == g) w += fr;
    acc += kv * w;
  }
  W[idx] = acc / ksum;
}

// ---------------------------------------------------------------------------
// 6) anomaly_map = W · md_grid · W^T
// ---------------------------------------------------------------------------
__global__ __launch_bounds__(256) void map_stage1_kernel(
    const float* __restrict__ md, const float* __restrict__ W,
    float* __restrict__ tmp) {  // 8 x 448 x 32
  int idx = blockIdx.x * 256 + threadIdx.x;
  if (idx >= 8 * 448 * 32) return;
  int gx = idx & 31;
  int y  = (idx >> 5) % 448;
  int b  = idx / (448 * 32);
  const float* w = W + y * 32;
  const float* m = md + b * 1024 + gx;
  float s = 0.f;
#pragma unroll
  for (int gy = 0; gy < 32; ++gy) s += w[gy] * m[gy * 32];
  tmp[idx] = s;
}

__global__ __launch_bounds__(256) void map_stage2_kernel(
    const float* __restrict__ tmp, const float* __restrict__ W,
    float* __restrict__ out) {  // 8 x 448 x 448
  int idx = blockIdx.x * 256 + threadIdx.x;
  if (idx >= 8 * 448 * 448) return;
  int x    = idx % 448;
  int ypos = idx / 448;  // b*448 + y
  const float* w = W + x * 32;
  const float* t = tmp + ypos * 32;
  float s = 0.f;
#pragma unroll
  for (int gx = 0; gx < 32; ++gx) s += w[gx] * t[gx];
  out[idx] = s;
}

// ---------------------------------------------------------------------------
extern "C" void kernel_launch(void* const* d_in, const int* in_sizes, int n_in,
                              void* d_out, int out_size, void* d_ws, size_t ws_size,
                              hipStream_t stream) {
  const float* features = (const float*)d_in[0];   // 8*1024*384
  const float* bank     = (const float*)d_in[1];   // 65536*384
  float* out = (float*)d_out;                      // [8 scores][8*448*448 map]

  char* ws = (char*)d_ws;
  char*  mb8     = ws;                              // 25,165,824 B
  char*  f8      = ws + 25165824;                   //  3,145,728 B
  float* sB      = (float*)(ws + 28311552);         //    262,144 B
  float* sA      = (float*)(ws + 28573696);         //     32,768 B
  float* partial = (float*)(ws + 28606464);         //  1,048,576 B
  float* md      = (float*)(ws + 29655040);         //     32,768 B
  float* W       = (float*)(ws + 29687808);         //     57,344 B
  float* tmp     = (float*)(ws + 29745152);         //    458,752 B

  quantize_rows_kernel<<<NROW_B / 4, 256, 0, stream>>>(bank, mb8, sB, NROW_B);
  quantize_rows_kernel<<<NROW_F / 4, 256, 0, stream>>>(features, f8, sA, NROW_F);
  maxsim_kernel<<<NWG, 512, 0, stream>>>(f8, mb8, sA, sB, partial);
  combine_kernel<<<NROW_F / 256, 256, 0, stream>>>(partial, md);
  topk_kernel<<<8, 256, 0, stream>>>(md, out);
  build_w_kernel<<<(448 * 32 + 255) / 256, 256, 0, stream>>>(W);
  map_stage1_kernel<<<(8 * 448 * 32 + 255) / 256, 256, 0, stream>>>(md, W, tmp);
  map_stage2_kernel<<<(8 * 448 * 448 + 255) / 256, 256, 0, stream>>>(tmp, W, out + 8);
}